// Round 7
// baseline (1126.265 us; speedup 1.0000x reference)
//
#include <hip/hip_runtime.h>

// ---------------- problem constants ----------------
constexpr int N_NODES = 65536;
constexpr int N_EDGES = 1048576;
constexpr int NPG     = 128;
constexpr int NGRAPH  = 512;
constexpr int KTOP    = 64;

// fast tanh: 1 - 2/(exp(2x)+1). NaN-free at +-inf, ~1e-7 abs error.
__device__ __forceinline__ float tanh_fast(float x) {
    float ex = __expf(2.0f * x);
    return 1.0f - __fdividef(2.0f, ex + 1.0f);
}

// ---------------- graph-structure kernels ----------------

__global__ __launch_bounds__(256) void init_deg_kernel(int* __restrict__ outdeg,
                                                       int* __restrict__ indeg) {
    int n = blockIdx.x * 256 + threadIdx.x;
    outdeg[n] = 1;   // self loop contributes to out-degree
    indeg[n]  = 0;   // real in-edges only (self handled separately)
}

// edge_index delivered as int32 by the harness (reference int64 -> const int*)
__global__ __launch_bounds__(256) void count_kernel(const int* __restrict__ ei,
                                                    int* __restrict__ outdeg,
                                                    int* __restrict__ indeg) {
    int e = blockIdx.x * 256 + threadIdx.x;
    int s = ei[e];
    int d = ei[N_EDGES + e];
    atomicAdd(&outdeg[s], 1);
    atomicAdd(&indeg[d], 1);
}

// single-block exclusive scan of indeg -> row_ptr (+ copy to cursor)
__global__ __launch_bounds__(1024) void scan_kernel(const int* __restrict__ indeg,
                                                    int* __restrict__ row_ptr,
                                                    int* __restrict__ cursor) {
    __shared__ int sums[1024];
    int t = threadIdx.x;
    int base = t * 64;
    int ssum = 0;
    for (int i = 0; i < 64; i++) ssum += indeg[base + i];
    sums[t] = ssum;
    __syncthreads();
    for (int off = 1; off < 1024; off <<= 1) {
        int v = (t >= off) ? sums[t - off] : 0;
        __syncthreads();
        sums[t] += v;
        __syncthreads();
    }
    int run = (t == 0) ? 0 : sums[t - 1];
    for (int i = 0; i < 64; i++) {
        int v = indeg[base + i];
        row_ptr[base + i] = run;
        cursor[base + i]  = run;
        run += v;
    }
    if (t == 1023) row_ptr[N_NODES] = sums[1023];
}

__global__ __launch_bounds__(256) void norm_beta_kernel(const int* __restrict__ outdeg,
                                                        const int* __restrict__ indeg,
                                                        float* __restrict__ normv,
                                                        float* __restrict__ betav) {
    int n = blockIdx.x * 256 + threadIdx.x;
    float nm = 1.0f / (float)outdeg[n];
    normv[n] = nm;
    betav[n] = nm * (float)(indeg[n] + 1);  // +1: self loop also carries the bias
}

__global__ __launch_bounds__(256) void fill_kernel(const int* __restrict__ ei,
                                                   int* __restrict__ cursor,
                                                   int* __restrict__ col) {
    int e = blockIdx.x * 256 + threadIdx.x;
    int s = ei[e];
    int d = ei[N_EDGES + e];
    int p = atomicAdd(&cursor[d], 1);
    col[p] = s;
}

// ---------------- aggregation (wave per node) ----------------
// out[d] = norm[d] * ( h[d] + sum_{e->d} h[col[e]] ), CH channels
// 4-edge unroll + next-iteration index prefetch (col padded +64 ints so the
// dead prefetch past e1 stays in-bounds; its values are never consumed).

template <int CH>
__global__ __launch_bounds__(256) void agg_kernel(const float* __restrict__ h,
                                                  const int* __restrict__ row_ptr,
                                                  const int* __restrict__ col,
                                                  const float* __restrict__ normv,
                                                  float* __restrict__ out) {
    int wid  = (blockIdx.x * 256 + threadIdx.x) >> 6;  // node id
    int lane = threadIdx.x & 63;
    int e  = row_ptr[wid];
    int e1 = row_ptr[wid + 1];
    if constexpr (CH == 256) {
        const float4* h4 = (const float4*)h;
        float4 acc = h4[(size_t)wid * 64 + lane];  // self loop
        if (e + 3 < e1) {
            int i0 = col[e], i1 = col[e + 1], i2 = col[e + 2], i3 = col[e + 3];
            for (;;) {
                int en = e + 4;
                bool more = (en + 3 < e1);
                // prefetch next iter's indices (in-bounds of padded col; unused if !more)
                int n0 = col[en], n1 = col[en + 1], n2 = col[en + 2], n3 = col[en + 3];
                float4 v0 = h4[(size_t)i0 * 64 + lane];
                float4 v1 = h4[(size_t)i1 * 64 + lane];
                float4 v2 = h4[(size_t)i2 * 64 + lane];
                float4 v3 = h4[(size_t)i3 * 64 + lane];
                acc.x += v0.x; acc.y += v0.y; acc.z += v0.z; acc.w += v0.w;
                acc.x += v1.x; acc.y += v1.y; acc.z += v1.z; acc.w += v1.w;
                acc.x += v2.x; acc.y += v2.y; acc.z += v2.z; acc.w += v2.w;
                acc.x += v3.x; acc.y += v3.y; acc.z += v3.z; acc.w += v3.w;
                e = en;
                if (!more) break;
                i0 = n0; i1 = n1; i2 = n2; i3 = n3;
            }
        }
        for (; e < e1; e++) {
            float4 v = h4[(size_t)col[e] * 64 + lane];
            acc.x += v.x; acc.y += v.y; acc.z += v.z; acc.w += v.w;
        }
        float nm = normv[wid];
        float4 o; o.x = acc.x * nm; o.y = acc.y * nm; o.z = acc.z * nm; o.w = acc.w * nm;
        ((float4*)out)[(size_t)wid * 64 + lane] = o;
    } else {  // CH == 128
        const float2* h2 = (const float2*)h;
        float2 acc = h2[(size_t)wid * 64 + lane];
        if (e + 3 < e1) {
            int i0 = col[e], i1 = col[e + 1], i2 = col[e + 2], i3 = col[e + 3];
            for (;;) {
                int en = e + 4;
                bool more = (en + 3 < e1);
                int n0 = col[en], n1 = col[en + 1], n2 = col[en + 2], n3 = col[en + 3];
                float2 v0 = h2[(size_t)i0 * 64 + lane];
                float2 v1 = h2[(size_t)i1 * 64 + lane];
                float2 v2 = h2[(size_t)i2 * 64 + lane];
                float2 v3 = h2[(size_t)i3 * 64 + lane];
                acc.x += v0.x; acc.y += v0.y;
                acc.x += v1.x; acc.y += v1.y;
                acc.x += v2.x; acc.y += v2.y;
                acc.x += v3.x; acc.y += v3.y;
                e = en;
                if (!more) break;
                i0 = n0; i1 = n1; i2 = n2; i3 = n3;
            }
        }
        for (; e < e1; e++) {
            float2 v = h2[(size_t)col[e] * 64 + lane];
            acc.x += v.x; acc.y += v.y;
        }
        float nm = normv[wid];
        float2 o; o.x = acc.x * nm; o.y = acc.y * nm;
        ((float2*)out)[(size_t)wid * 64 + lane] = o;
    }
}

// ---------------- fp32 GEMM + tanh(acc + beta*b) epilogue ----------------
// A: [M, KDIM] (pre-scaled agg), W: [KDIM, 256], out: [M, 256]
// 128x128 tile, BK=32, 256 threads, 8x8 acc/thread split 64 apart so every
// ds_read_b128 pattern is broadcast or <=2-way bank aliased (free, m136).
// Register double-buffer: tile k+1's global loads issue right after the
// barrier and complete under tile k's FMAs (waitcnt lands at next LDS-store).

template <int KDIM>
__global__ __launch_bounds__(256) void gemm_tanh_kernel(const float* __restrict__ A,
                                                        const float* __restrict__ W,
                                                        const float* __restrict__ bias,
                                                        const float* __restrict__ betav,
                                                        float* __restrict__ out) {
    constexpr int BM = 128, BN = 128, BK = 32;
    __shared__ float As[BK][BM + 4];   // row stride 132 floats (528 B = 33*16)
    __shared__ float Bs[BK][BN + 4];
    int t  = threadIdx.x;
    int tx = t & 15, ty = t >> 4;      // 16 x 16 thread grid
    int rowBase = blockIdx.x * BM;
    int colBase = blockIdx.y * BN;

    float4 ra[4], rb[4];
    // A tile: 128x32 = 1024 float4, 4/thread; idx -> r=idx>>3 (row), c4=idx&7
    // B tile: 32x128 = 1024 float4, 4/thread; idx -> r=idx>>5 (k),   c4=idx&31
    #pragma unroll
    for (int i = 0; i < 4; i++) {
        int idx = t + i * 256;
        ra[i] = *(const float4*)&A[(size_t)(rowBase + (idx >> 3)) * KDIM + (idx & 7) * 4];
        rb[i] = *(const float4*)&W[(size_t)(idx >> 5) * 256 + colBase + (idx & 31) * 4];
    }

    float acc[8][8] = {};
    for (int k0 = 0; k0 < KDIM; k0 += BK) {
        #pragma unroll
        for (int i = 0; i < 4; i++) {
            int idx = t + i * 256;
            int r = idx >> 3, c4 = idx & 7;
            As[c4 * 4 + 0][r] = ra[i].x;
            As[c4 * 4 + 1][r] = ra[i].y;
            As[c4 * 4 + 2][r] = ra[i].z;
            As[c4 * 4 + 3][r] = ra[i].w;
        }
        #pragma unroll
        for (int i = 0; i < 4; i++) {
            int idx = t + i * 256;
            *(float4*)&Bs[idx >> 5][(idx & 31) * 4] = rb[i];
        }
        __syncthreads();
        if (k0 + BK < KDIM) {
            int kn = k0 + BK;
            #pragma unroll
            for (int i = 0; i < 4; i++) {
                int idx = t + i * 256;
                ra[i] = *(const float4*)&A[(size_t)(rowBase + (idx >> 3)) * KDIM + kn + (idx & 7) * 4];
                rb[i] = *(const float4*)&W[(size_t)(kn + (idx >> 5)) * 256 + colBase + (idx & 31) * 4];
            }
        }
        #pragma unroll
        for (int k = 0; k < BK; k++) {
            float a[8], b[8];
            float4 a0 = *(const float4*)&As[k][ty * 4];
            float4 a1 = *(const float4*)&As[k][64 + ty * 4];
            a[0]=a0.x; a[1]=a0.y; a[2]=a0.z; a[3]=a0.w;
            a[4]=a1.x; a[5]=a1.y; a[6]=a1.z; a[7]=a1.w;
            float4 b0 = *(const float4*)&Bs[k][tx * 4];
            float4 b1 = *(const float4*)&Bs[k][64 + tx * 4];
            b[0]=b0.x; b[1]=b0.y; b[2]=b0.z; b[3]=b0.w;
            b[4]=b1.x; b[5]=b1.y; b[6]=b1.z; b[7]=b1.w;
            #pragma unroll
            for (int i = 0; i < 8; i++)
                #pragma unroll
                for (int j = 0; j < 8; j++)
                    acc[i][j] += a[i] * b[j];
        }
        __syncthreads();
    }
    // epilogue: rows ty*4+i (+0/+64), cols tx*4+j (+0/+64)
    #pragma unroll
    for (int half = 0; half < 2; half++) {
        #pragma unroll
        for (int i = 0; i < 4; i++) {
            int r  = rowBase + half * 64 + ty * 4 + i;
            int ai = half * 4 + i;
            float bt = betav[r];
            float4 o;
            o.x = tanh_fast(acc[ai][0] + bt * bias[colBase + tx * 4 + 0]);
            o.y = tanh_fast(acc[ai][1] + bt * bias[colBase + tx * 4 + 1]);
            o.z = tanh_fast(acc[ai][2] + bt * bias[colBase + tx * 4 + 2]);
            o.w = tanh_fast(acc[ai][3] + bt * bias[colBase + tx * 4 + 3]);
            *(float4*)&out[(size_t)r * 256 + colBase + tx * 4] = o;
            o.x = tanh_fast(acc[ai][4] + bt * bias[colBase + 64 + tx * 4 + 0]);
            o.y = tanh_fast(acc[ai][5] + bt * bias[colBase + 64 + tx * 4 + 1]);
            o.z = tanh_fast(acc[ai][6] + bt * bias[colBase + 64 + tx * 4 + 2]);
            o.w = tanh_fast(acc[ai][7] + bt * bias[colBase + 64 + tx * 4 + 3]);
            *(float4*)&out[(size_t)r * 256 + colBase + 64 + tx * 4] = o;
        }
    }
}

// ---------------- layer-4 GEMV: s_lin[n] = h3[n] . W4 ----------------

__global__ __launch_bounds__(256) void gemv_kernel(const float* __restrict__ h,
                                                   const float* __restrict__ w4,
                                                   float* __restrict__ s_lin) {
    int wid  = (blockIdx.x * 256 + threadIdx.x) >> 6;
    int lane = threadIdx.x & 63;
    const float4* h4 = (const float4*)h;
    const float4* w  = (const float4*)w4;
    float4 a = h4[(size_t)wid * 64 + lane];
    float4 b = w[lane];
    float s = a.x * b.x + a.y * b.y + a.z * b.z + a.w * b.w;
    s += __shfl_xor(s, 32); s += __shfl_xor(s, 16); s += __shfl_xor(s, 8);
    s += __shfl_xor(s, 4);  s += __shfl_xor(s, 2);  s += __shfl_xor(s, 1);
    if (lane == 0) s_lin[wid] = s;
}

// score[d] = tanh(norm*(s_lin[d] + sum s_lin[src]) + beta*b4)
__global__ __launch_bounds__(256) void agg_scalar_kernel(const float* __restrict__ s_lin,
                                                         const int* __restrict__ row_ptr,
                                                         const int* __restrict__ col,
                                                         const float* __restrict__ normv,
                                                         const float* __restrict__ betav,
                                                         const float* __restrict__ b4,
                                                         float* __restrict__ scores) {
    int wid  = (blockIdx.x * 256 + threadIdx.x) >> 6;
    int lane = threadIdx.x & 63;
    int e0 = row_ptr[wid], e1 = row_ptr[wid + 1];
    float sum = (lane == 0) ? s_lin[wid] : 0.0f;
    for (int e = e0 + lane; e < e1; e += 64) sum += s_lin[col[e]];
    sum += __shfl_xor(sum, 32); sum += __shfl_xor(sum, 16); sum += __shfl_xor(sum, 8);
    sum += __shfl_xor(sum, 4);  sum += __shfl_xor(sum, 2);  sum += __shfl_xor(sum, 1);
    if (lane == 0) scores[wid] = tanh_fast(normv[wid] * sum + betav[wid] * b4[0]);
}

// ---------------- per-graph descending bitonic sort, keep top-64 values ----------------

__global__ __launch_bounds__(128) void sort_kernel(const float* __restrict__ scores,
                                                   float* __restrict__ topk) {
    __shared__ float v[128];
    int b = blockIdx.x, t = threadIdx.x;
    v[t] = scores[b * NPG + t];
    __syncthreads();
    for (int k = 2; k <= 128; k <<= 1) {
        for (int j = k >> 1; j > 0; j >>= 1) {
            int ixj = t ^ j;
            if (ixj > t) {
                bool up = ((t & k) == 0);
                float a = v[t], c = v[ixj];
                bool sw = up ? (a < c) : (a > c);  // descending
                if (sw) { v[t] = c; v[ixj] = a; }
            }
            __syncthreads();
        }
    }
    if (t < KTOP) topk[b * KTOP + t] = v[t];
}

// ---------------- head: conv1(stride TLD) -> pool -> conv2 -> fc1 -> fc2 ----------------
// conv1 stride 769 over padded input whose only nonzeros are the first 64
// entries: output pos 0 = dot(top, w[0..63]); positions >=1 see only zeros.

__global__ __launch_bounds__(128) void head_kernel(const float* __restrict__ topk,
                                                   const float* __restrict__ c1w,
                                                   const float* __restrict__ c1b,
                                                   const float* __restrict__ c2w,
                                                   const float* __restrict__ c2b,
                                                   const float* __restrict__ f1w,
                                                   const float* __restrict__ f1b,
                                                   const float* __restrict__ f2w,
                                                   const float* __restrict__ f2b,
                                                   float* __restrict__ out) {
    __shared__ float top[64];
    __shared__ float pool[16][32];
    __shared__ float dense[896];
    __shared__ float fc1o[128];
    int b = blockIdx.x, t = threadIdx.x;
    if (t < 64) top[t] = topk[b * KTOP + t];
    __syncthreads();
    if (t < 16) {
        float a = c1b[t];
        for (int i = 0; i < 64; i++) a += c1w[t * 769 + i] * top[i];
        float v0 = fmaxf(a, 0.0f);
        float r  = fmaxf(c1b[t], 0.0f);
        pool[t][0] = fmaxf(v0, r);
        for (int p = 1; p < 32; p++) pool[t][p] = r;
    }
    __syncthreads();
    for (int idx = t; idx < 896; idx += 128) {
        int o = idx / 28, p = idx % 28;
        float a = c2b[o];
        for (int i = 0; i < 16; i++) {
            #pragma unroll
            for (int tt = 0; tt < 5; tt++)
                a += c2w[o * 80 + i * 5 + tt] * pool[i][p + tt];
        }
        dense[idx] = fmaxf(a, 0.0f);
    }
    __syncthreads();
    {
        float a = f1b[t];
        for (int i = 0; i < 896; i++) a += f1w[i * 128 + t] * dense[i];
        fc1o[t] = fmaxf(a, 0.0f);
    }
    __syncthreads();
    if (t < 10) {
        float a = f2b[t];
        for (int i = 0; i < 128; i++) a += f2w[i * 10 + t] * fc1o[i];
        out[b * 10 + t] = a;
    }
}

// ---------------- launch ----------------

extern "C" void kernel_launch(void* const* d_in, const int* in_sizes, int n_in,
                              void* d_out, int out_size, void* d_ws, size_t ws_size,
                              hipStream_t stream) {
    const float* x   = (const float*)d_in[0];
    const int*   ei  = (const int*)d_in[1];   // int32 per harness contract
    // d_in[2] = batch (int32, contiguous equal-size; unused)
    const float* W1 = (const float*)d_in[3];
    const float* b1 = (const float*)d_in[4];
    const float* W2 = (const float*)d_in[5];
    const float* b2 = (const float*)d_in[6];
    const float* W3 = (const float*)d_in[7];
    const float* b3 = (const float*)d_in[8];
    const float* W4 = (const float*)d_in[9];
    const float* b4 = (const float*)d_in[10];
    const float* c1w = (const float*)d_in[11];
    const float* c1b = (const float*)d_in[12];
    const float* c2w = (const float*)d_in[13];
    const float* c2b = (const float*)d_in[14];
    const float* f1w = (const float*)d_in[15];
    const float* f1b = (const float*)d_in[16];
    const float* f2w = (const float*)d_in[17];
    const float* f2b = (const float*)d_in[18];
    float* out = (float*)d_out;

    // workspace layout (~134 MB)
    char* ws = (char*)d_ws;
    float* bufA = (float*)ws;                            // 64 MB  [N,256] (or [N,128])
    float* bufB = (float*)(ws + ((size_t)64 << 20));     // 64 MB  [N,256]
    char* p = ws + ((size_t)128 << 20);
    auto take = [&](size_t bytes) { char* q = p; p += (bytes + 255) & ~(size_t)255; return q; };
    int*   outdeg  = (int*)take(N_NODES * 4);
    int*   indeg   = (int*)take(N_NODES * 4);
    int*   row_ptr = (int*)take((N_NODES + 1) * 4);
    int*   cursor  = (int*)take(N_NODES * 4);
    int*   col     = (int*)take(((size_t)N_EDGES + 64) * 4);  // +64 pad for prefetch
    float* normv   = (float*)take(N_NODES * 4);
    float* betav   = (float*)take(N_NODES * 4);
    float* s_lin   = (float*)take(N_NODES * 4);
    float* scores  = (float*)take(N_NODES * 4);
    float* topk    = (float*)take(NGRAPH * KTOP * 4);

    // graph structure
    init_deg_kernel<<<N_NODES / 256, 256, 0, stream>>>(outdeg, indeg);
    count_kernel<<<N_EDGES / 256, 256, 0, stream>>>(ei, outdeg, indeg);
    scan_kernel<<<1, 1024, 0, stream>>>(indeg, row_ptr, cursor);
    norm_beta_kernel<<<N_NODES / 256, 256, 0, stream>>>(outdeg, indeg, normv, betav);
    fill_kernel<<<N_EDGES / 256, 256, 0, stream>>>(ei, cursor, col);

    dim3 gemmGrid(N_NODES / 128, 2);

    // layer 1: aggregate x (128ch, norm-scaled) -> GEMM W1 -> tanh
    agg_kernel<128><<<N_NODES / 4, 256, 0, stream>>>(x, row_ptr, col, normv, bufA);
    gemm_tanh_kernel<128><<<gemmGrid, 256, 0, stream>>>(bufA, W1, b1, betav, bufB);
    // layer 2
    agg_kernel<256><<<N_NODES / 4, 256, 0, stream>>>(bufB, row_ptr, col, normv, bufA);
    gemm_tanh_kernel<256><<<gemmGrid, 256, 0, stream>>>(bufA, W2, b2, betav, bufB);
    // layer 3
    agg_kernel<256><<<N_NODES / 4, 256, 0, stream>>>(bufB, row_ptr, col, normv, bufA);
    gemm_tanh_kernel<256><<<gemmGrid, 256, 0, stream>>>(bufA, W3, b3, betav, bufB);
    // layer 4: GEMV then scalar aggregate + tanh
    gemv_kernel<<<N_NODES / 4, 256, 0, stream>>>(bufB, W4, s_lin);
    agg_scalar_kernel<<<N_NODES / 4, 256, 0, stream>>>(s_lin, row_ptr, col, normv, betav, b4, scores);

    // sort-pool + head
    sort_kernel<<<NGRAPH, 128, 0, stream>>>(scores, topk);
    head_kernel<<<NGRAPH, 128, 0, stream>>>(topk, c1w, c1b, c2w, c2b, f1w, f1b, f2w, f2b, out);
}

// Round 10
// 913.554 us; speedup vs baseline: 1.2328x; 1.2328x over previous
//
#include <hip/hip_runtime.h>

// ---------------- problem constants ----------------
constexpr int N_NODES = 65536;
constexpr int N_EDGES = 1048576;
constexpr int NPG     = 128;
constexpr int NGRAPH  = 512;
constexpr int KTOP    = 64;

using short8 = __attribute__((ext_vector_type(8))) short;
using f32x4  = __attribute__((ext_vector_type(4))) float;

// fast tanh: 1 - 2/(exp(2x)+1). NaN-free at +-inf, ~1e-7 abs error.
__device__ __forceinline__ float tanh_fast(float x) {
    float ex = __expf(2.0f * x);
    return 1.0f - __fdividef(2.0f, ex + 1.0f);
}
// bf16 round-to-nearest-even (returns low-16 bit pattern)
__device__ __forceinline__ unsigned bf16_rne(float f) {
    unsigned u = __float_as_uint(f);
    return (u + 0x7FFFu + ((u >> 16) & 1u)) >> 16;
}
__device__ __forceinline__ float bf16_to_f(unsigned h) {
    return __uint_as_float(h << 16);
}

// ---------------- graph-structure kernels ----------------

__global__ __launch_bounds__(256) void init_deg_kernel(int* __restrict__ outdeg,
                                                       int* __restrict__ indeg) {
    int n = blockIdx.x * 256 + threadIdx.x;
    outdeg[n] = 1;   // self loop contributes to out-degree
    indeg[n]  = 0;
}

__global__ __launch_bounds__(256) void count_kernel(const int* __restrict__ ei,
                                                    int* __restrict__ outdeg,
                                                    int* __restrict__ indeg) {
    int e = blockIdx.x * 256 + threadIdx.x;
    atomicAdd(&outdeg[ei[e]], 1);
    atomicAdd(&indeg[ei[N_EDGES + e]], 1);
}

__global__ __launch_bounds__(1024) void scan_kernel(const int* __restrict__ indeg,
                                                    int* __restrict__ row_ptr,
                                                    int* __restrict__ cursor) {
    __shared__ int sums[1024];
    int t = threadIdx.x;
    int base = t * 64;
    int ssum = 0;
    for (int i = 0; i < 64; i++) ssum += indeg[base + i];
    sums[t] = ssum;
    __syncthreads();
    for (int off = 1; off < 1024; off <<= 1) {
        int v = (t >= off) ? sums[t - off] : 0;
        __syncthreads();
        sums[t] += v;
        __syncthreads();
    }
    int run = (t == 0) ? 0 : sums[t - 1];
    for (int i = 0; i < 64; i++) {
        int v = indeg[base + i];
        row_ptr[base + i] = run;
        cursor[base + i]  = run;
        run += v;
    }
    if (t == 1023) row_ptr[N_NODES] = sums[1023];
}

__global__ __launch_bounds__(256) void norm_beta_kernel(const int* __restrict__ outdeg,
                                                        const int* __restrict__ indeg,
                                                        float* __restrict__ normv,
                                                        float* __restrict__ betav) {
    int n = blockIdx.x * 256 + threadIdx.x;
    float nm = 1.0f / (float)outdeg[n];
    normv[n] = nm;
    betav[n] = nm * (float)(indeg[n] + 1);
}

__global__ __launch_bounds__(256) void fill_kernel(const int* __restrict__ ei,
                                                   int* __restrict__ cursor,
                                                   int* __restrict__ col) {
    int e = blockIdx.x * 256 + threadIdx.x;
    int s = ei[e];
    int d = ei[N_EDGES + e];
    int p = atomicAdd(&cursor[d], 1);
    col[p] = s;
}

// ---------------- W split: fp32 [K,256] -> transposed bf16 hi/lo [256][K] ----------------

__global__ __launch_bounds__(256) void wsplit_kernel(const float* __restrict__ W,
                                                     ushort* __restrict__ WhT,
                                                     ushort* __restrict__ WlT, int K) {
    int idx = blockIdx.x * 256 + threadIdx.x;   // over K*256
    int k = idx >> 8, c = idx & 255;
    float w = W[idx];
    unsigned h = bf16_rne(w);
    unsigned l = bf16_rne(w - bf16_to_f(h));
    WhT[c * K + k] = (ushort)h;
    WlT[c * K + k] = (ushort)l;
}

// ---------------- aggregation (wave per node) -> bf16 hi/lo output ----------------
// val[d] = norm[d] * ( h[d] + sum_{e->d} h[col[e]] ); emit bf16 split (exact to 2^-16).

template <int CH>
__global__ __launch_bounds__(256) void agg_bf16_kernel(const float* __restrict__ h,
                                                       const int* __restrict__ row_ptr,
                                                       const int* __restrict__ col,
                                                       const float* __restrict__ normv,
                                                       ushort* __restrict__ Ah,
                                                       ushort* __restrict__ Al) {
    int wid  = (blockIdx.x * 256 + threadIdx.x) >> 6;
    int lane = threadIdx.x & 63;
    int e  = row_ptr[wid];
    int e1 = row_ptr[wid + 1];
    if constexpr (CH == 256) {
        const float4* h4 = (const float4*)h;
        float4 acc = h4[(size_t)wid * 64 + lane];  // self loop
        if (e + 3 < e1) {
            int i0 = col[e], i1 = col[e + 1], i2 = col[e + 2], i3 = col[e + 3];
            for (;;) {
                int en = e + 4;
                bool more = (en + 3 < e1);
                int n0 = col[en], n1 = col[en + 1], n2 = col[en + 2], n3 = col[en + 3];
                float4 v0 = h4[(size_t)i0 * 64 + lane];
                float4 v1 = h4[(size_t)i1 * 64 + lane];
                float4 v2 = h4[(size_t)i2 * 64 + lane];
                float4 v3 = h4[(size_t)i3 * 64 + lane];
                acc.x += v0.x; acc.y += v0.y; acc.z += v0.z; acc.w += v0.w;
                acc.x += v1.x; acc.y += v1.y; acc.z += v1.z; acc.w += v1.w;
                acc.x += v2.x; acc.y += v2.y; acc.z += v2.z; acc.w += v2.w;
                acc.x += v3.x; acc.y += v3.y; acc.z += v3.z; acc.w += v3.w;
                e = en;
                if (!more) break;
                i0 = n0; i1 = n1; i2 = n2; i3 = n3;
            }
        }
        for (; e < e1; e++) {
            float4 v = h4[(size_t)col[e] * 64 + lane];
            acc.x += v.x; acc.y += v.y; acc.z += v.z; acc.w += v.w;
        }
        float nm = normv[wid];
        float ox = acc.x * nm, oy = acc.y * nm, oz = acc.z * nm, ow = acc.w * nm;
        unsigned hx = bf16_rne(ox), hy = bf16_rne(oy), hz = bf16_rne(oz), hw = bf16_rne(ow);
        unsigned lx = bf16_rne(ox - bf16_to_f(hx));
        unsigned ly = bf16_rne(oy - bf16_to_f(hy));
        unsigned lz = bf16_rne(oz - bf16_to_f(hz));
        unsigned lw = bf16_rne(ow - bf16_to_f(hw));
        size_t base = (size_t)wid * 256 + lane * 4;
        *(uint2*)&Ah[base] = make_uint2(hx | (hy << 16), hz | (hw << 16));
        *(uint2*)&Al[base] = make_uint2(lx | (ly << 16), lz | (lw << 16));
    } else {  // CH == 128
        const float2* h2 = (const float2*)h;
        float2 acc = h2[(size_t)wid * 64 + lane];
        if (e + 3 < e1) {
            int i0 = col[e], i1 = col[e + 1], i2 = col[e + 2], i3 = col[e + 3];
            for (;;) {
                int en = e + 4;
                bool more = (en + 3 < e1);
                int n0 = col[en], n1 = col[en + 1], n2 = col[en + 2], n3 = col[en + 3];
                float2 v0 = h2[(size_t)i0 * 64 + lane];
                float2 v1 = h2[(size_t)i1 * 64 + lane];
                float2 v2 = h2[(size_t)i2 * 64 + lane];
                float2 v3 = h2[(size_t)i3 * 64 + lane];
                acc.x += v0.x; acc.y += v0.y;
                acc.x += v1.x; acc.y += v1.y;
                acc.x += v2.x; acc.y += v2.y;
                acc.x += v3.x; acc.y += v3.y;
                e = en;
                if (!more) break;
                i0 = n0; i1 = n1; i2 = n2; i3 = n3;
            }
        }
        for (; e < e1; e++) {
            float2 v = h2[(size_t)col[e] * 64 + lane];
            acc.x += v.x; acc.y += v.y;
        }
        float nm = normv[wid];
        float ox = acc.x * nm, oy = acc.y * nm;
        unsigned hx = bf16_rne(ox), hy = bf16_rne(oy);
        unsigned lx = bf16_rne(ox - bf16_to_f(hx));
        unsigned ly = bf16_rne(oy - bf16_to_f(hy));
        size_t base = (size_t)wid * 128 + lane * 2;
        *(unsigned*)&Ah[base] = hx | (hy << 16);
        *(unsigned*)&Al[base] = lx | (ly << 16);
    }
}

// ---------------- split-bf16 MFMA GEMM + tanh epilogue ----------------
// C = A*W via 3 bf16 MFMAs (ah*wh + ah*wl + al*wh): ~fp32 accuracy, MFMA rate/3.
// A hi/lo bf16 [M][KDIM]; W hi/lo bf16 transposed [256 cols][KDIM].
// Block 128x128, 4 waves; wave owns 32 rows x 128 cols = 2x8 16x16 tiles.
// Frag layout (16x16x32): A row=l&15, k=(l>>4)*8+j ; B col=l&15, same k.
// LDS [128][40] shorts: 80B row stride (20 words, gcd(20,32)=4) -> <=2-way = free.

template <int KDIM>
__global__ __launch_bounds__(256) void gemm_mfma_tanh(const ushort* __restrict__ Ah,
                                                      const ushort* __restrict__ Al,
                                                      const ushort* __restrict__ WhT,
                                                      const ushort* __restrict__ WlT,
                                                      const float* __restrict__ bias,
                                                      const float* __restrict__ betav,
                                                      float* __restrict__ out) {
    __shared__ ushort Ahs[128][40], Als[128][40], Whs[128][40], Wls[128][40];
    int t    = threadIdx.x;
    int lane = t & 63, wv = t >> 6;
    int rowBase = blockIdx.x * 128;
    int colBase = blockIdx.y * 128;
    f32x4 acc[2][8] = {};

    for (int k0 = 0; k0 < KDIM; k0 += 32) {
        // stage A hi/lo: 128 rows x 32 k = 512 8-short chunks per array, 2/thread
        #pragma unroll
        for (int i = 0; i < 2; i++) {
            int idx = t + i * 256;
            int r = idx >> 2, kq = idx & 3;
            size_t g = (size_t)(rowBase + r) * KDIM + k0 + kq * 8;
            *(short8*)&Ahs[r][kq * 8] = *(const short8*)&Ah[g];
            *(short8*)&Als[r][kq * 8] = *(const short8*)&Al[g];
        }
        // stage W hi/lo tiles (cols colBase..+127)
        #pragma unroll
        for (int i = 0; i < 2; i++) {
            int idx = t + i * 256;
            int c = idx >> 2, kq = idx & 3;
            size_t g = (size_t)(colBase + c) * KDIM + k0 + kq * 8;
            *(short8*)&Whs[c][kq * 8] = *(const short8*)&WhT[g];
            *(short8*)&Wls[c][kq * 8] = *(const short8*)&WlT[g];
        }
        __syncthreads();
        int rA = wv * 32 + (lane & 15);
        int kb = (lane >> 4) * 8;
        short8 ah0 = *(const short8*)&Ahs[rA][kb];
        short8 ah1 = *(const short8*)&Ahs[rA + 16][kb];
        short8 al0 = *(const short8*)&Als[rA][kb];
        short8 al1 = *(const short8*)&Als[rA + 16][kb];
        #pragma unroll
        for (int ct = 0; ct < 8; ct++) {
            int cW = ct * 16 + (lane & 15);
            short8 wh = *(const short8*)&Whs[cW][kb];
            short8 wl = *(const short8*)&Wls[cW][kb];
            acc[0][ct] = __builtin_amdgcn_mfma_f32_16x16x32_bf16(ah0, wh, acc[0][ct], 0, 0, 0);
            acc[0][ct] = __builtin_amdgcn_mfma_f32_16x16x32_bf16(ah0, wl, acc[0][ct], 0, 0, 0);
            acc[0][ct] = __builtin_amdgcn_mfma_f32_16x16x32_bf16(al0, wh, acc[0][ct], 0, 0, 0);
            acc[1][ct] = __builtin_amdgcn_mfma_f32_16x16x32_bf16(ah1, wh, acc[1][ct], 0, 0, 0);
            acc[1][ct] = __builtin_amdgcn_mfma_f32_16x16x32_bf16(ah1, wl, acc[1][ct], 0, 0, 0);
            acc[1][ct] = __builtin_amdgcn_mfma_f32_16x16x32_bf16(al1, wh, acc[1][ct], 0, 0, 0);
        }
        __syncthreads();
    }
    // epilogue: C/D layout col=l&15, row=(l>>4)*4+j (m89-verified)
    int cb = colBase + (lane & 15);
    #pragma unroll
    for (int rt = 0; rt < 2; rt++) {
        int rb = rowBase + wv * 32 + rt * 16 + (lane >> 4) * 4;
        #pragma unroll
        for (int j = 0; j < 4; j++) {
            int row = rb + j;
            float bt = betav[row];
            #pragma unroll
            for (int ct = 0; ct < 8; ct++) {
                int c = cb + ct * 16;
                out[(size_t)row * 256 + c] = tanh_fast(acc[rt][ct][j] + bt * bias[c]);
            }
        }
    }
}

// ---------------- layer-4 GEMV: s_lin[n] = h3[n] . W4 ----------------

__global__ __launch_bounds__(256) void gemv_kernel(const float* __restrict__ h,
                                                   const float* __restrict__ w4,
                                                   float* __restrict__ s_lin) {
    int wid  = (blockIdx.x * 256 + threadIdx.x) >> 6;
    int lane = threadIdx.x & 63;
    const float4* h4 = (const float4*)h;
    const float4* w  = (const float4*)w4;
    float4 a = h4[(size_t)wid * 64 + lane];
    float4 b = w[lane];
    float s = a.x * b.x + a.y * b.y + a.z * b.z + a.w * b.w;
    s += __shfl_xor(s, 32); s += __shfl_xor(s, 16); s += __shfl_xor(s, 8);
    s += __shfl_xor(s, 4);  s += __shfl_xor(s, 2);  s += __shfl_xor(s, 1);
    if (lane == 0) s_lin[wid] = s;
}

__global__ __launch_bounds__(256) void agg_scalar_kernel(const float* __restrict__ s_lin,
                                                         const int* __restrict__ row_ptr,
                                                         const int* __restrict__ col,
                                                         const float* __restrict__ normv,
                                                         const float* __restrict__ betav,
                                                         const float* __restrict__ b4,
                                                         float* __restrict__ scores) {
    int wid  = (blockIdx.x * 256 + threadIdx.x) >> 6;
    int lane = threadIdx.x & 63;
    int e0 = row_ptr[wid], e1 = row_ptr[wid + 1];
    float sum = (lane == 0) ? s_lin[wid] : 0.0f;
    for (int e = e0 + lane; e < e1; e += 64) sum += s_lin[col[e]];
    sum += __shfl_xor(sum, 32); sum += __shfl_xor(sum, 16); sum += __shfl_xor(sum, 8);
    sum += __shfl_xor(sum, 4);  sum += __shfl_xor(sum, 2);  sum += __shfl_xor(sum, 1);
    if (lane == 0) scores[wid] = tanh_fast(normv[wid] * sum + betav[wid] * b4[0]);
}

// ---------------- per-graph descending bitonic sort, keep top-64 values ----------------

__global__ __launch_bounds__(128) void sort_kernel(const float* __restrict__ scores,
                                                   float* __restrict__ topk) {
    __shared__ float v[128];
    int b = blockIdx.x, t = threadIdx.x;
    v[t] = scores[b * NPG + t];
    __syncthreads();
    for (int k = 2; k <= 128; k <<= 1) {
        for (int j = k >> 1; j > 0; j >>= 1) {
            int ixj = t ^ j;
            if (ixj > t) {
                bool up = ((t & k) == 0);
                float a = v[t], c = v[ixj];
                bool sw = up ? (a < c) : (a > c);
                if (sw) { v[t] = c; v[ixj] = a; }
            }
            __syncthreads();
        }
    }
    if (t < KTOP) topk[b * KTOP + t] = v[t];
}

// ---------------- head ----------------

__global__ __launch_bounds__(128) void head_kernel(const float* __restrict__ topk,
                                                   const float* __restrict__ c1w,
                                                   const float* __restrict__ c1b,
                                                   const float* __restrict__ c2w,
                                                   const float* __restrict__ c2b,
                                                   const float* __restrict__ f1w,
                                                   const float* __restrict__ f1b,
                                                   const float* __restrict__ f2w,
                                                   const float* __restrict__ f2b,
                                                   float* __restrict__ out) {
    __shared__ float top[64];
    __shared__ float pool[16][32];
    __shared__ float dense[896];
    __shared__ float fc1o[128];
    int b = blockIdx.x, t = threadIdx.x;
    if (t < 64) top[t] = topk[b * KTOP + t];
    __syncthreads();
    if (t < 16) {
        float a = c1b[t];
        for (int i = 0; i < 64; i++) a += c1w[t * 769 + i] * top[i];
        float v0 = fmaxf(a, 0.0f);
        float r  = fmaxf(c1b[t], 0.0f);
        pool[t][0] = fmaxf(v0, r);
        for (int p = 1; p < 32; p++) pool[t][p] = r;
    }
    __syncthreads();
    for (int idx = t; idx < 896; idx += 128) {
        int o = idx / 28, p = idx % 28;
        float a = c2b[o];
        for (int i = 0; i < 16; i++) {
            #pragma unroll
            for (int tt = 0; tt < 5; tt++)
                a += c2w[o * 80 + i * 5 + tt] * pool[i][p + tt];
        }
        dense[idx] = fmaxf(a, 0.0f);
    }
    __syncthreads();
    {
        float a = f1b[t];
        for (int i = 0; i < 896; i++) a += f1w[i * 128 + t] * dense[i];
        fc1o[t] = fmaxf(a, 0.0f);
    }
    __syncthreads();
    if (t < 10) {
        float a = f2b[t];
        for (int i = 0; i < 128; i++) a += f2w[i * 10 + t] * fc1o[i];
        out[b * 10 + t] = a;
    }
}

// ---------------- launch ----------------

extern "C" void kernel_launch(void* const* d_in, const int* in_sizes, int n_in,
                              void* d_out, int out_size, void* d_ws, size_t ws_size,
                              hipStream_t stream) {
    const float* x   = (const float*)d_in[0];
    const int*   ei  = (const int*)d_in[1];   // int32 per harness contract
    const float* W1 = (const float*)d_in[3];
    const float* b1 = (const float*)d_in[4];
    const float* W2 = (const float*)d_in[5];
    const float* b2 = (const float*)d_in[6];
    const float* W3 = (const float*)d_in[7];
    const float* b3 = (const float*)d_in[8];
    const float* W4 = (const float*)d_in[9];
    const float* b4 = (const float*)d_in[10];
    const float* c1w = (const float*)d_in[11];
    const float* c1b = (const float*)d_in[12];
    const float* c2w = (const float*)d_in[13];
    const float* c2b = (const float*)d_in[14];
    const float* f1w = (const float*)d_in[15];
    const float* f1b = (const float*)d_in[16];
    const float* f2w = (const float*)d_in[17];
    const float* f2b = (const float*)d_in[18];
    float* out = (float*)d_out;

    // workspace layout (~139 MB)
    char* ws = (char*)d_ws;
    float*  bufB = (float*)ws;                             // 64 MB fp32 activations
    ushort* AhG  = (ushort*)(ws + ((size_t)64 << 20));     // 32 MB bf16-hi
    ushort* AlG  = (ushort*)(ws + ((size_t)96 << 20));     // 32 MB bf16-lo
    char* p = ws + ((size_t)128 << 20);
    auto take = [&](size_t bytes) { char* q = p; p += (bytes + 255) & ~(size_t)255; return q; };
    int*    outdeg  = (int*)take(N_NODES * 4);
    int*    indeg   = (int*)take(N_NODES * 4);
    int*    row_ptr = (int*)take((N_NODES + 1) * 4);
    int*    cursor  = (int*)take(N_NODES * 4);
    int*    col     = (int*)take(((size_t)N_EDGES + 64) * 4);  // +64 pad for prefetch
    float*  normv   = (float*)take(N_NODES * 4);
    float*  betav   = (float*)take(N_NODES * 4);
    float*  s_lin   = (float*)take(N_NODES * 4);
    float*  scores  = (float*)take(N_NODES * 4);
    float*  topk    = (float*)take(NGRAPH * KTOP * 4);
    ushort* W1hT = (ushort*)take(128 * 256 * 2);
    ushort* W1lT = (ushort*)take(128 * 256 * 2);
    ushort* W2hT = (ushort*)take(256 * 256 * 2);
    ushort* W2lT = (ushort*)take(256 * 256 * 2);
    ushort* W3hT = (ushort*)take(256 * 256 * 2);
    ushort* W3lT = (ushort*)take(256 * 256 * 2);

    // graph structure + weight splits
    init_deg_kernel<<<N_NODES / 256, 256, 0, stream>>>(outdeg, indeg);
    count_kernel<<<N_EDGES / 256, 256, 0, stream>>>(ei, outdeg, indeg);
    scan_kernel<<<1, 1024, 0, stream>>>(indeg, row_ptr, cursor);
    norm_beta_kernel<<<N_NODES / 256, 256, 0, stream>>>(outdeg, indeg, normv, betav);
    fill_kernel<<<N_EDGES / 256, 256, 0, stream>>>(ei, cursor, col);
    wsplit_kernel<<<128, 256, 0, stream>>>(W1, W1hT, W1lT, 128);
    wsplit_kernel<<<256, 256, 0, stream>>>(W2, W2hT, W2lT, 256);
    wsplit_kernel<<<256, 256, 0, stream>>>(W3, W3hT, W3lT, 256);

    dim3 gemmGrid(N_NODES / 128, 2);

    // layer 1
    agg_bf16_kernel<128><<<N_NODES / 4, 256, 0, stream>>>(x, row_ptr, col, normv, AhG, AlG);
    gemm_mfma_tanh<128><<<gemmGrid, 256, 0, stream>>>(AhG, AlG, W1hT, W1lT, b1, betav, bufB);
    // layer 2
    agg_bf16_kernel<256><<<N_NODES / 4, 256, 0, stream>>>(bufB, row_ptr, col, normv, AhG, AlG);
    gemm_mfma_tanh<256><<<gemmGrid, 256, 0, stream>>>(AhG, AlG, W2hT, W2lT, b2, betav, bufB);
    // layer 3
    agg_bf16_kernel<256><<<N_NODES / 4, 256, 0, stream>>>(bufB, row_ptr, col, normv, AhG, AlG);
    gemm_mfma_tanh<256><<<gemmGrid, 256, 0, stream>>>(AhG, AlG, W3hT, W3lT, b3, betav, bufB);
    // layer 4
    gemv_kernel<<<N_NODES / 4, 256, 0, stream>>>(bufB, W4, s_lin);
    agg_scalar_kernel<<<N_NODES / 4, 256, 0, stream>>>(s_lin, row_ptr, col, normv, betav, b4, scores);

    // sort-pool + head
    sort_kernel<<<NGRAPH, 128, 0, stream>>>(scores, topk);
    head_kernel<<<NGRAPH, 128, 0, stream>>>(topk, c1w, c1b, c2w, c2b, f1w, f1b, f2w, f2b, out);
}

// Round 11
// 737.609 us; speedup vs baseline: 1.5269x; 1.2385x over previous
//
#include <hip/hip_runtime.h>

// ---------------- problem constants ----------------
constexpr int N_NODES = 65536;
constexpr int N_EDGES = 1048576;
constexpr int NPG     = 128;
constexpr int NGRAPH  = 512;
constexpr int KTOP    = 64;

using short8 = __attribute__((ext_vector_type(8))) short;
using f32x4  = __attribute__((ext_vector_type(4))) float;

// fast tanh: 1 - 2/(exp(2x)+1). NaN-free at +-inf, ~1e-7 abs error.
__device__ __forceinline__ float tanh_fast(float x) {
    float ex = __expf(2.0f * x);
    return 1.0f - __fdividef(2.0f, ex + 1.0f);
}
// bf16 round-to-nearest-even (returns low-16 bit pattern)
__device__ __forceinline__ unsigned bf16_rne(float f) {
    unsigned u = __float_as_uint(f);
    return (u + 0x7FFFu + ((u >> 16) & 1u)) >> 16;
}
__device__ __forceinline__ float bf16_to_f(unsigned h) {
    return __uint_as_float(h << 16);
}

// ---------------- graph-structure kernels ----------------

__global__ __launch_bounds__(256) void init_deg_kernel(int* __restrict__ outdeg,
                                                       int* __restrict__ indeg) {
    int n = blockIdx.x * 256 + threadIdx.x;
    outdeg[n] = 1;   // self loop contributes to out-degree
    indeg[n]  = 0;
}

__global__ __launch_bounds__(256) void count_kernel(const int* __restrict__ ei,
                                                    int* __restrict__ outdeg,
                                                    int* __restrict__ indeg) {
    int e = blockIdx.x * 256 + threadIdx.x;
    atomicAdd(&outdeg[ei[e]], 1);
    atomicAdd(&indeg[ei[N_EDGES + e]], 1);
}

__global__ __launch_bounds__(1024) void scan_kernel(const int* __restrict__ indeg,
                                                    int* __restrict__ row_ptr,
                                                    int* __restrict__ cursor) {
    __shared__ int sums[1024];
    int t = threadIdx.x;
    int base = t * 64;
    int ssum = 0;
    for (int i = 0; i < 64; i++) ssum += indeg[base + i];
    sums[t] = ssum;
    __syncthreads();
    for (int off = 1; off < 1024; off <<= 1) {
        int v = (t >= off) ? sums[t - off] : 0;
        __syncthreads();
        sums[t] += v;
        __syncthreads();
    }
    int run = (t == 0) ? 0 : sums[t - 1];
    for (int i = 0; i < 64; i++) {
        int v = indeg[base + i];
        row_ptr[base + i] = run;
        cursor[base + i]  = run;
        run += v;
    }
    if (t == 1023) row_ptr[N_NODES] = sums[1023];
}

__global__ __launch_bounds__(256) void norm_beta_kernel(const int* __restrict__ outdeg,
                                                        const int* __restrict__ indeg,
                                                        float* __restrict__ normv,
                                                        float* __restrict__ betav) {
    int n = blockIdx.x * 256 + threadIdx.x;
    float nm = 1.0f / (float)outdeg[n];
    normv[n] = nm;
    betav[n] = nm * (float)(indeg[n] + 1);
}

__global__ __launch_bounds__(256) void fill_kernel(const int* __restrict__ ei,
                                                   int* __restrict__ cursor,
                                                   int* __restrict__ col) {
    int e = blockIdx.x * 256 + threadIdx.x;
    int s = ei[e];
    int d = ei[N_EDGES + e];
    int p = atomicAdd(&cursor[d], 1);
    col[p] = s;
}

// ---------------- W split: fp32 [K,256] -> transposed bf16 hi/lo [256][K] ----------------

__global__ __launch_bounds__(256) void wsplit_kernel(const float* __restrict__ W,
                                                     ushort* __restrict__ WhT,
                                                     ushort* __restrict__ WlT, int K) {
    int idx = blockIdx.x * 256 + threadIdx.x;   // over K*256
    int k = idx >> 8, c = idx & 255;
    float w = W[idx];
    unsigned h = bf16_rne(w);
    unsigned l = bf16_rne(w - bf16_to_f(h));
    WhT[c * K + k] = (ushort)h;
    WlT[c * K + k] = (ushort)l;
}

// ---------------- layer-1 aggregation: fp32 x (128 ch) -> bf16 hi/lo ----------------

__global__ __launch_bounds__(256) void agg_x_kernel(const float* __restrict__ h,
                                                    const int* __restrict__ row_ptr,
                                                    const int* __restrict__ col,
                                                    const float* __restrict__ normv,
                                                    ushort* __restrict__ Ah,
                                                    ushort* __restrict__ Al) {
    int wid  = (blockIdx.x * 256 + threadIdx.x) >> 6;
    int lane = threadIdx.x & 63;
    int e  = row_ptr[wid];
    int e1 = row_ptr[wid + 1];
    const float2* h2 = (const float2*)h;
    float2 acc = h2[(size_t)wid * 64 + lane];  // self loop
    if (e + 3 < e1) {
        int i0 = col[e], i1 = col[e + 1], i2 = col[e + 2], i3 = col[e + 3];
        for (;;) {
            int en = e + 4;
            bool more = (en + 3 < e1);
            int n0 = col[en], n1 = col[en + 1], n2 = col[en + 2], n3 = col[en + 3];
            float2 v0 = h2[(size_t)i0 * 64 + lane];
            float2 v1 = h2[(size_t)i1 * 64 + lane];
            float2 v2 = h2[(size_t)i2 * 64 + lane];
            float2 v3 = h2[(size_t)i3 * 64 + lane];
            acc.x += v0.x; acc.y += v0.y;
            acc.x += v1.x; acc.y += v1.y;
            acc.x += v2.x; acc.y += v2.y;
            acc.x += v3.x; acc.y += v3.y;
            e = en;
            if (!more) break;
            i0 = n0; i1 = n1; i2 = n2; i3 = n3;
        }
    }
    for (; e < e1; e++) {
        float2 v = h2[(size_t)col[e] * 64 + lane];
        acc.x += v.x; acc.y += v.y;
    }
    float nm = normv[wid];
    float ox = acc.x * nm, oy = acc.y * nm;
    unsigned hx = bf16_rne(ox), hy = bf16_rne(oy);
    unsigned lx = bf16_rne(ox - bf16_to_f(hx));
    unsigned ly = bf16_rne(oy - bf16_to_f(hy));
    size_t base = (size_t)wid * 128 + lane * 2;
    *(unsigned*)&Ah[base] = hx | (hy << 16);
    *(unsigned*)&Al[base] = lx | (ly << 16);
}

// ---------------- layers-2/3 aggregation: bf16 h (256 ch) -> bf16 hi/lo ----------------
// Gathers 512B/edge (uint2 per lane = 4 bf16 channels), fp32 accumulate,
// exact hi/lo split of the fp32 sum for the GEMM.

__global__ __launch_bounds__(256) void agg_h_kernel(const ushort* __restrict__ hb,
                                                    const int* __restrict__ row_ptr,
                                                    const int* __restrict__ col,
                                                    const float* __restrict__ normv,
                                                    ushort* __restrict__ Ah,
                                                    ushort* __restrict__ Al) {
    int wid  = (blockIdx.x * 256 + threadIdx.x) >> 6;
    int lane = threadIdx.x & 63;
    int e  = row_ptr[wid];
    int e1 = row_ptr[wid + 1];
    const uint2* h2 = (const uint2*)hb;   // 64 uint2 per node (256 bf16 ch)
    uint2 s = h2[(size_t)wid * 64 + lane];  // self loop
    float a0 = bf16_to_f(s.x & 0xffff), a1 = bf16_to_f(s.x >> 16);
    float a2 = bf16_to_f(s.y & 0xffff), a3 = bf16_to_f(s.y >> 16);
    if (e + 3 < e1) {
        int i0 = col[e], i1 = col[e + 1], i2 = col[e + 2], i3 = col[e + 3];
        for (;;) {
            int en = e + 4;
            bool more = (en + 3 < e1);
            int n0 = col[en], n1 = col[en + 1], n2 = col[en + 2], n3 = col[en + 3];
            uint2 v0 = h2[(size_t)i0 * 64 + lane];
            uint2 v1 = h2[(size_t)i1 * 64 + lane];
            uint2 v2 = h2[(size_t)i2 * 64 + lane];
            uint2 v3 = h2[(size_t)i3 * 64 + lane];
            a0 += bf16_to_f(v0.x & 0xffff); a1 += bf16_to_f(v0.x >> 16);
            a2 += bf16_to_f(v0.y & 0xffff); a3 += bf16_to_f(v0.y >> 16);
            a0 += bf16_to_f(v1.x & 0xffff); a1 += bf16_to_f(v1.x >> 16);
            a2 += bf16_to_f(v1.y & 0xffff); a3 += bf16_to_f(v1.y >> 16);
            a0 += bf16_to_f(v2.x & 0xffff); a1 += bf16_to_f(v2.x >> 16);
            a2 += bf16_to_f(v2.y & 0xffff); a3 += bf16_to_f(v2.y >> 16);
            a0 += bf16_to_f(v3.x & 0xffff); a1 += bf16_to_f(v3.x >> 16);
            a2 += bf16_to_f(v3.y & 0xffff); a3 += bf16_to_f(v3.y >> 16);
            e = en;
            if (!more) break;
            i0 = n0; i1 = n1; i2 = n2; i3 = n3;
        }
    }
    for (; e < e1; e++) {
        uint2 v = h2[(size_t)col[e] * 64 + lane];
        a0 += bf16_to_f(v.x & 0xffff); a1 += bf16_to_f(v.x >> 16);
        a2 += bf16_to_f(v.y & 0xffff); a3 += bf16_to_f(v.y >> 16);
    }
    float nm = normv[wid];
    float ox = a0 * nm, oy = a1 * nm, oz = a2 * nm, ow = a3 * nm;
    unsigned hx = bf16_rne(ox), hy = bf16_rne(oy), hz = bf16_rne(oz), hw = bf16_rne(ow);
    unsigned lx = bf16_rne(ox - bf16_to_f(hx));
    unsigned ly = bf16_rne(oy - bf16_to_f(hy));
    unsigned lz = bf16_rne(oz - bf16_to_f(hz));
    unsigned lw = bf16_rne(ow - bf16_to_f(hw));
    size_t base = (size_t)wid * 256 + lane * 4;
    *(uint2*)&Ah[base] = make_uint2(hx | (hy << 16), hz | (hw << 16));
    *(uint2*)&Al[base] = make_uint2(lx | (ly << 16), lz | (lw << 16));
}

// ---------------- split-bf16 MFMA GEMM + tanh epilogue -> bf16 output ----------------
// C = A*W via 3 bf16 MFMAs (ah*wh + ah*wl + al*wh): ~fp32 accuracy, MFMA rate/3.
// Output stored as bf16 (h in [-1,1]; 2^-9 rel storage error).

template <int KDIM>
__global__ __launch_bounds__(256) void gemm_mfma_tanh(const ushort* __restrict__ Ah,
                                                      const ushort* __restrict__ Al,
                                                      const ushort* __restrict__ WhT,
                                                      const ushort* __restrict__ WlT,
                                                      const float* __restrict__ bias,
                                                      const float* __restrict__ betav,
                                                      ushort* __restrict__ out) {
    __shared__ ushort Ahs[128][40], Als[128][40], Whs[128][40], Wls[128][40];
    int t    = threadIdx.x;
    int lane = t & 63, wv = t >> 6;
    int rowBase = blockIdx.x * 128;
    int colBase = blockIdx.y * 128;
    f32x4 acc[2][8] = {};

    for (int k0 = 0; k0 < KDIM; k0 += 32) {
        #pragma unroll
        for (int i = 0; i < 2; i++) {
            int idx = t + i * 256;
            int r = idx >> 2, kq = idx & 3;
            size_t g = (size_t)(rowBase + r) * KDIM + k0 + kq * 8;
            *(short8*)&Ahs[r][kq * 8] = *(const short8*)&Ah[g];
            *(short8*)&Als[r][kq * 8] = *(const short8*)&Al[g];
        }
        #pragma unroll
        for (int i = 0; i < 2; i++) {
            int idx = t + i * 256;
            int c = idx >> 2, kq = idx & 3;
            size_t g = (size_t)(colBase + c) * KDIM + k0 + kq * 8;
            *(short8*)&Whs[c][kq * 8] = *(const short8*)&WhT[g];
            *(short8*)&Wls[c][kq * 8] = *(const short8*)&WlT[g];
        }
        __syncthreads();
        int rA = wv * 32 + (lane & 15);
        int kb = (lane >> 4) * 8;
        short8 ah0 = *(const short8*)&Ahs[rA][kb];
        short8 ah1 = *(const short8*)&Ahs[rA + 16][kb];
        short8 al0 = *(const short8*)&Als[rA][kb];
        short8 al1 = *(const short8*)&Als[rA + 16][kb];
        #pragma unroll
        for (int ct = 0; ct < 8; ct++) {
            int cW = ct * 16 + (lane & 15);
            short8 wh = *(const short8*)&Whs[cW][kb];
            short8 wl = *(const short8*)&Wls[cW][kb];
            acc[0][ct] = __builtin_amdgcn_mfma_f32_16x16x32_bf16(ah0, wh, acc[0][ct], 0, 0, 0);
            acc[0][ct] = __builtin_amdgcn_mfma_f32_16x16x32_bf16(ah0, wl, acc[0][ct], 0, 0, 0);
            acc[0][ct] = __builtin_amdgcn_mfma_f32_16x16x32_bf16(al0, wh, acc[0][ct], 0, 0, 0);
            acc[1][ct] = __builtin_amdgcn_mfma_f32_16x16x32_bf16(ah1, wh, acc[1][ct], 0, 0, 0);
            acc[1][ct] = __builtin_amdgcn_mfma_f32_16x16x32_bf16(ah1, wl, acc[1][ct], 0, 0, 0);
            acc[1][ct] = __builtin_amdgcn_mfma_f32_16x16x32_bf16(al1, wh, acc[1][ct], 0, 0, 0);
        }
        __syncthreads();
    }
    // epilogue: C/D layout col=l&15, row=(l>>4)*4+j (m89-verified); bf16 stores
    int cb = colBase + (lane & 15);
    #pragma unroll
    for (int rt = 0; rt < 2; rt++) {
        int rb = rowBase + wv * 32 + rt * 16 + (lane >> 4) * 4;
        #pragma unroll
        for (int j = 0; j < 4; j++) {
            int row = rb + j;
            float bt = betav[row];
            #pragma unroll
            for (int ct = 0; ct < 8; ct++) {
                int c = cb + ct * 16;
                out[(size_t)row * 256 + c] =
                    (ushort)bf16_rne(tanh_fast(acc[rt][ct][j] + bt * bias[c]));
            }
        }
    }
}

// ---------------- layer-4 GEMV: s_lin[n] = h3[n] . W4 (bf16 h3) ----------------

__global__ __launch_bounds__(256) void gemv_kernel(const ushort* __restrict__ hb,
                                                   const float* __restrict__ w4,
                                                   float* __restrict__ s_lin) {
    int wid  = (blockIdx.x * 256 + threadIdx.x) >> 6;
    int lane = threadIdx.x & 63;
    const uint2* h2 = (const uint2*)hb;
    uint2 a = h2[(size_t)wid * 64 + lane];
    float4 b = ((const float4*)w4)[lane];
    float s = bf16_to_f(a.x & 0xffff) * b.x + bf16_to_f(a.x >> 16) * b.y +
              bf16_to_f(a.y & 0xffff) * b.z + bf16_to_f(a.y >> 16) * b.w;
    s += __shfl_xor(s, 32); s += __shfl_xor(s, 16); s += __shfl_xor(s, 8);
    s += __shfl_xor(s, 4);  s += __shfl_xor(s, 2);  s += __shfl_xor(s, 1);
    if (lane == 0) s_lin[wid] = s;
}

__global__ __launch_bounds__(256) void agg_scalar_kernel(const float* __restrict__ s_lin,
                                                         const int* __restrict__ row_ptr,
                                                         const int* __restrict__ col,
                                                         const float* __restrict__ normv,
                                                         const float* __restrict__ betav,
                                                         const float* __restrict__ b4,
                                                         float* __restrict__ scores) {
    int wid  = (blockIdx.x * 256 + threadIdx.x) >> 6;
    int lane = threadIdx.x & 63;
    int e0 = row_ptr[wid], e1 = row_ptr[wid + 1];
    float sum = (lane == 0) ? s_lin[wid] : 0.0f;
    for (int e = e0 + lane; e < e1; e += 64) sum += s_lin[col[e]];
    sum += __shfl_xor(sum, 32); sum += __shfl_xor(sum, 16); sum += __shfl_xor(sum, 8);
    sum += __shfl_xor(sum, 4);  sum += __shfl_xor(sum, 2);  sum += __shfl_xor(sum, 1);
    if (lane == 0) scores[wid] = tanh_fast(normv[wid] * sum + betav[wid] * b4[0]);
}

// ---------------- per-graph descending bitonic sort, keep top-64 values ----------------

__global__ __launch_bounds__(128) void sort_kernel(const float* __restrict__ scores,
                                                   float* __restrict__ topk) {
    __shared__ float v[128];
    int b = blockIdx.x, t = threadIdx.x;
    v[t] = scores[b * NPG + t];
    __syncthreads();
    for (int k = 2; k <= 128; k <<= 1) {
        for (int j = k >> 1; j > 0; j >>= 1) {
            int ixj = t ^ j;
            if (ixj > t) {
                bool up = ((t & k) == 0);
                float a = v[t], c = v[ixj];
                bool sw = up ? (a < c) : (a > c);
                if (sw) { v[t] = c; v[ixj] = a; }
            }
            __syncthreads();
        }
    }
    if (t < KTOP) topk[b * KTOP + t] = v[t];
}

// ---------------- head ----------------

__global__ __launch_bounds__(128) void head_kernel(const float* __restrict__ topk,
                                                   const float* __restrict__ c1w,
                                                   const float* __restrict__ c1b,
                                                   const float* __restrict__ c2w,
                                                   const float* __restrict__ c2b,
                                                   const float* __restrict__ f1w,
                                                   const float* __restrict__ f1b,
                                                   const float* __restrict__ f2w,
                                                   const float* __restrict__ f2b,
                                                   float* __restrict__ out) {
    __shared__ float top[64];
    __shared__ float pool[16][32];
    __shared__ float dense[896];
    __shared__ float fc1o[128];
    int b = blockIdx.x, t = threadIdx.x;
    if (t < 64) top[t] = topk[b * KTOP + t];
    __syncthreads();
    if (t < 16) {
        float a = c1b[t];
        for (int i = 0; i < 64; i++) a += c1w[t * 769 + i] * top[i];
        float v0 = fmaxf(a, 0.0f);
        float r  = fmaxf(c1b[t], 0.0f);
        pool[t][0] = fmaxf(v0, r);
        for (int p = 1; p < 32; p++) pool[t][p] = r;
    }
    __syncthreads();
    for (int idx = t; idx < 896; idx += 128) {
        int o = idx / 28, p = idx % 28;
        float a = c2b[o];
        for (int i = 0; i < 16; i++) {
            #pragma unroll
            for (int tt = 0; tt < 5; tt++)
                a += c2w[o * 80 + i * 5 + tt] * pool[i][p + tt];
        }
        dense[idx] = fmaxf(a, 0.0f);
    }
    __syncthreads();
    {
        float a = f1b[t];
        for (int i = 0; i < 896; i++) a += f1w[i * 128 + t] * dense[i];
        fc1o[t] = fmaxf(a, 0.0f);
    }
    __syncthreads();
    if (t < 10) {
        float a = f2b[t];
        for (int i = 0; i < 128; i++) a += f2w[i * 10 + t] * fc1o[i];
        out[b * 10 + t] = a;
    }
}

// ---------------- launch ----------------

extern "C" void kernel_launch(void* const* d_in, const int* in_sizes, int n_in,
                              void* d_out, int out_size, void* d_ws, size_t ws_size,
                              hipStream_t stream) {
    const float* x   = (const float*)d_in[0];
    const int*   ei  = (const int*)d_in[1];   // int32 per harness contract
    const float* W1 = (const float*)d_in[3];
    const float* b1 = (const float*)d_in[4];
    const float* W2 = (const float*)d_in[5];
    const float* b2 = (const float*)d_in[6];
    const float* W3 = (const float*)d_in[7];
    const float* b3 = (const float*)d_in[8];
    const float* W4 = (const float*)d_in[9];
    const float* b4 = (const float*)d_in[10];
    const float* c1w = (const float*)d_in[11];
    const float* c1b = (const float*)d_in[12];
    const float* c2w = (const float*)d_in[13];
    const float* c2b = (const float*)d_in[14];
    const float* f1w = (const float*)d_in[15];
    const float* f1b = (const float*)d_in[16];
    const float* f2w = (const float*)d_in[17];
    const float* f2b = (const float*)d_in[18];
    float* out = (float*)d_out;

    // workspace layout (~106 MB)
    char* ws = (char*)d_ws;
    ushort* hbB  = (ushort*)ws;                            // 32 MB bf16 activations [N][256]
    ushort* AhG  = (ushort*)(ws + ((size_t)32 << 20));     // 32 MB bf16-hi
    ushort* AlG  = (ushort*)(ws + ((size_t)64 << 20));     // 32 MB bf16-lo
    char* p = ws + ((size_t)96 << 20);
    auto take = [&](size_t bytes) { char* q = p; p += (bytes + 255) & ~(size_t)255; return q; };
    int*    outdeg  = (int*)take(N_NODES * 4);
    int*    indeg   = (int*)take(N_NODES * 4);
    int*    row_ptr = (int*)take((N_NODES + 1) * 4);
    int*    cursor  = (int*)take(N_NODES * 4);
    int*    col     = (int*)take(((size_t)N_EDGES + 64) * 4);  // +64 pad for prefetch
    float*  normv   = (float*)take(N_NODES * 4);
    float*  betav   = (float*)take(N_NODES * 4);
    float*  s_lin   = (float*)take(N_NODES * 4);
    float*  scores  = (float*)take(N_NODES * 4);
    float*  topk    = (float*)take(NGRAPH * KTOP * 4);
    ushort* W1hT = (ushort*)take(128 * 256 * 2);
    ushort* W1lT = (ushort*)take(128 * 256 * 2);
    ushort* W2hT = (ushort*)take(256 * 256 * 2);
    ushort* W2lT = (ushort*)take(256 * 256 * 2);
    ushort* W3hT = (ushort*)take(256 * 256 * 2);
    ushort* W3lT = (ushort*)take(256 * 256 * 2);

    // graph structure + weight splits
    init_deg_kernel<<<N_NODES / 256, 256, 0, stream>>>(outdeg, indeg);
    count_kernel<<<N_EDGES / 256, 256, 0, stream>>>(ei, outdeg, indeg);
    scan_kernel<<<1, 1024, 0, stream>>>(indeg, row_ptr, cursor);
    norm_beta_kernel<<<N_NODES / 256, 256, 0, stream>>>(outdeg, indeg, normv, betav);
    fill_kernel<<<N_EDGES / 256, 256, 0, stream>>>(ei, cursor, col);
    wsplit_kernel<<<128, 256, 0, stream>>>(W1, W1hT, W1lT, 128);
    wsplit_kernel<<<256, 256, 0, stream>>>(W2, W2hT, W2lT, 256);
    wsplit_kernel<<<256, 256, 0, stream>>>(W3, W3hT, W3lT, 256);

    dim3 gemmGrid(N_NODES / 128, 2);

    // layer 1: fp32 x gather -> hi/lo; MFMA GEMM -> bf16 h1
    agg_x_kernel<<<N_NODES / 4, 256, 0, stream>>>(x, row_ptr, col, normv, AhG, AlG);
    gemm_mfma_tanh<128><<<gemmGrid, 256, 0, stream>>>(AhG, AlG, W1hT, W1lT, b1, betav, hbB);
    // layer 2: bf16 gather (512B/edge) -> hi/lo; GEMM -> bf16 h2
    agg_h_kernel<<<N_NODES / 4, 256, 0, stream>>>(hbB, row_ptr, col, normv, AhG, AlG);
    gemm_mfma_tanh<256><<<gemmGrid, 256, 0, stream>>>(AhG, AlG, W2hT, W2lT, b2, betav, hbB);
    // layer 3
    agg_h_kernel<<<N_NODES / 4, 256, 0, stream>>>(hbB, row_ptr, col, normv, AhG, AlG);
    gemm_mfma_tanh<256><<<gemmGrid, 256, 0, stream>>>(AhG, AlG, W3hT, W3lT, b3, betav, hbB);
    // layer 4
    gemv_kernel<<<N_NODES / 4, 256, 0, stream>>>(hbB, W4, s_lin);
    agg_scalar_kernel<<<N_NODES / 4, 256, 0, stream>>>(s_lin, row_ptr, col, normv, betav, b4, scores);

    // sort-pool + head
    sort_kernel<<<NGRAPH, 128, 0, stream>>>(scores, topk);
    head_kernel<<<NGRAPH, 128, 0, stream>>>(topk, c1w, c1b, c2w, c2b, f1w, f1b, f2w, f2b, out);
}

// Round 13
// 707.177 us; speedup vs baseline: 1.5926x; 1.0430x over previous
//
#include <hip/hip_runtime.h>

// ---------------- problem constants ----------------
constexpr int N_NODES = 65536;
constexpr int N_EDGES = 1048576;
constexpr int NPG     = 128;
constexpr int NGRAPH  = 512;
constexpr int KTOP    = 64;
constexpr int RSHIFT  = 13;   // 8 node ranges of 8192 -> XCD-confined atomics

using short8 = __attribute__((ext_vector_type(8))) short;
using f32x4  = __attribute__((ext_vector_type(4))) float;

// fast tanh: 1 - 2/(exp(2x)+1). NaN-free at +-inf, ~1e-7 abs error.
__device__ __forceinline__ float tanh_fast(float x) {
    float ex = __expf(2.0f * x);
    return 1.0f - __fdividef(2.0f, ex + 1.0f);
}
// bf16 round-to-nearest-even (returns low-16 bit pattern)
__device__ __forceinline__ unsigned bf16_rne(float f) {
    unsigned u = __float_as_uint(f);
    return (u + 0x7FFFu + ((u >> 16) & 1u)) >> 16;
}
__device__ __forceinline__ float bf16_to_f(unsigned h) {
    return __uint_as_float(h << 16);
}

// ---------------- graph-structure kernels ----------------

__global__ __launch_bounds__(256) void init_deg_kernel(int* __restrict__ outdeg,
                                                       int* __restrict__ indeg) {
    int n = blockIdx.x * 256 + threadIdx.x;
    outdeg[n] = 1;   // self loop contributes to out-degree
    indeg[n]  = 0;
}

// Range-confined degree count: block's node range = blockIdx&7 (matches
// round-robin blockIdx->XCD mapping), so atomics stay in one XCD's L2.
__global__ __launch_bounds__(256) void count_range_kernel(const int* __restrict__ ei,
                                                          int* __restrict__ outdeg,
                                                          int* __restrict__ indeg) {
    int r  = blockIdx.x & 7;
    int lo = r << RSHIFT, hi = lo + (1 << RSHIFT);
    int slice = blockIdx.x >> 3;                 // 0..255
    int start = slice * (N_EDGES / 256);
    int end   = start + (N_EDGES / 256);
    for (int i = start + threadIdx.x; i < end; i += 256) {
        int s = ei[i];
        int d = ei[N_EDGES + i];
        if (s >= lo && s < hi) atomicAdd(&outdeg[s], 1);
        if (d >= lo && d < hi) atomicAdd(&indeg[d], 1);
    }
}

__global__ __launch_bounds__(1024) void scan_kernel(const int* __restrict__ indeg,
                                                    int* __restrict__ row_ptr,
                                                    int* __restrict__ cursor) {
    __shared__ int sums[1024];
    int t = threadIdx.x;
    int base = t * 64;
    int ssum = 0;
    for (int i = 0; i < 64; i++) ssum += indeg[base + i];
    sums[t] = ssum;
    __syncthreads();
    for (int off = 1; off < 1024; off <<= 1) {
        int v = (t >= off) ? sums[t - off] : 0;
        __syncthreads();
        sums[t] += v;
        __syncthreads();
    }
    int run = (t == 0) ? 0 : sums[t - 1];
    for (int i = 0; i < 64; i++) {
        int v = indeg[base + i];
        row_ptr[base + i] = run;
        cursor[base + i]  = run;
        run += v;
    }
    if (t == 1023) row_ptr[N_NODES] = sums[1023];
}

__global__ __launch_bounds__(256) void norm_beta_kernel(const int* __restrict__ outdeg,
                                                        const int* __restrict__ indeg,
                                                        float* __restrict__ normv,
                                                        float* __restrict__ betav) {
    int n = blockIdx.x * 256 + threadIdx.x;
    float nm = 1.0f / (float)outdeg[n];
    normv[n] = nm;
    betav[n] = nm * (float)(indeg[n] + 1);
}

// Range-confined CSR fill: cursor slice (32KB) + col slice (~512KB) stay in
// one XCD's L2 -> dirty lines written back once (kills 64B/4B write-amp).
__global__ __launch_bounds__(256) void fill_range_kernel(const int* __restrict__ ei,
                                                         int* __restrict__ cursor,
                                                         int* __restrict__ col) {
    int r  = blockIdx.x & 7;
    int lo = r << RSHIFT, hi = lo + (1 << RSHIFT);
    int slice = blockIdx.x >> 3;
    int start = slice * (N_EDGES / 256);
    int end   = start + (N_EDGES / 256);
    for (int i = start + threadIdx.x; i < end; i += 256) {
        int d = ei[N_EDGES + i];
        if (d >= lo && d < hi) {
            int p = atomicAdd(&cursor[d], 1);
            col[p] = ei[i];
        }
    }
}

// ---------------- x -> bf16 pre-convert ----------------

__global__ __launch_bounds__(256) void xconv_kernel(const float* __restrict__ x,
                                                    ushort* __restrict__ xb) {
    int idx = blockIdx.x * 256 + threadIdx.x;    // over 2M float4
    float4 v = ((const float4*)x)[idx];
    unsigned a = bf16_rne(v.x) | (bf16_rne(v.y) << 16);
    unsigned b = bf16_rne(v.z) | (bf16_rne(v.w) << 16);
    ((uint2*)xb)[idx] = make_uint2(a, b);
}

// ---------------- W split: fp32 [K,256] -> transposed bf16 hi/lo [256][K] ----------------

__global__ __launch_bounds__(256) void wsplit_kernel(const float* __restrict__ W,
                                                     ushort* __restrict__ WhT,
                                                     ushort* __restrict__ WlT, int K) {
    int idx = blockIdx.x * 256 + threadIdx.x;   // over K*256
    int k = idx >> 8, c = idx & 255;
    float w = W[idx];
    unsigned h = bf16_rne(w);
    unsigned l = bf16_rne(w - bf16_to_f(h));
    WhT[c * K + k] = (ushort)h;
    WlT[c * K + k] = (ushort)l;
}

// ---------------- layer-1 aggregation: bf16 x (128 ch) -> bf16 hi/lo ----------------
// Gathers 256B/edge (uint per lane = 2 bf16 channels), fp32 accumulate.

__global__ __launch_bounds__(256) void agg_x_kernel(const ushort* __restrict__ xb,
                                                    const int* __restrict__ row_ptr,
                                                    const int* __restrict__ col,
                                                    const float* __restrict__ normv,
                                                    ushort* __restrict__ Ah,
                                                    ushort* __restrict__ Al) {
    int wid  = (blockIdx.x * 256 + threadIdx.x) >> 6;
    int lane = threadIdx.x & 63;
    int e  = row_ptr[wid];
    int e1 = row_ptr[wid + 1];
    const uint* h1 = (const uint*)xb;   // 64 uints per node (128 bf16 ch)
    uint s = h1[(size_t)wid * 64 + lane];  // self loop
    float a0 = bf16_to_f(s & 0xffff), a1 = bf16_to_f(s >> 16);
    if (e + 3 < e1) {
        int i0 = col[e], i1 = col[e + 1], i2 = col[e + 2], i3 = col[e + 3];
        for (;;) {
            int en = e + 4;
            bool more = (en + 3 < e1);
            int n0 = col[en], n1 = col[en + 1], n2 = col[en + 2], n3 = col[en + 3];
            uint v0 = h1[(size_t)i0 * 64 + lane];
            uint v1 = h1[(size_t)i1 * 64 + lane];
            uint v2 = h1[(size_t)i2 * 64 + lane];
            uint v3 = h1[(size_t)i3 * 64 + lane];
            a0 += bf16_to_f(v0 & 0xffff); a1 += bf16_to_f(v0 >> 16);
            a0 += bf16_to_f(v1 & 0xffff); a1 += bf16_to_f(v1 >> 16);
            a0 += bf16_to_f(v2 & 0xffff); a1 += bf16_to_f(v2 >> 16);
            a0 += bf16_to_f(v3 & 0xffff); a1 += bf16_to_f(v3 >> 16);
            e = en;
            if (!more) break;
            i0 = n0; i1 = n1; i2 = n2; i3 = n3;
        }
    }
    for (; e < e1; e++) {
        uint v = h1[(size_t)col[e] * 64 + lane];
        a0 += bf16_to_f(v & 0xffff); a1 += bf16_to_f(v >> 16);
    }
    float nm = normv[wid];
    float ox = a0 * nm, oy = a1 * nm;
    unsigned hx = bf16_rne(ox), hy = bf16_rne(oy);
    unsigned lx = bf16_rne(ox - bf16_to_f(hx));
    unsigned ly = bf16_rne(oy - bf16_to_f(hy));
    size_t base = (size_t)wid * 128 + lane * 2;
    *(unsigned*)&Ah[base] = hx | (hy << 16);
    *(unsigned*)&Al[base] = lx | (ly << 16);
}

// ---------------- layers-2/3 aggregation: bf16 h (256 ch) -> bf16 hi/lo ----------------

__global__ __launch_bounds__(256) void agg_h_kernel(const ushort* __restrict__ hb,
                                                    const int* __restrict__ row_ptr,
                                                    const int* __restrict__ col,
                                                    const float* __restrict__ normv,
                                                    ushort* __restrict__ Ah,
                                                    ushort* __restrict__ Al) {
    int wid  = (blockIdx.x * 256 + threadIdx.x) >> 6;
    int lane = threadIdx.x & 63;
    int e  = row_ptr[wid];
    int e1 = row_ptr[wid + 1];
    const uint2* h2 = (const uint2*)hb;   // 64 uint2 per node (256 bf16 ch)
    uint2 s = h2[(size_t)wid * 64 + lane];  // self loop
    float a0 = bf16_to_f(s.x & 0xffff), a1 = bf16_to_f(s.x >> 16);
    float a2 = bf16_to_f(s.y & 0xffff), a3 = bf16_to_f(s.y >> 16);
    if (e + 3 < e1) {
        int i0 = col[e], i1 = col[e + 1], i2 = col[e + 2], i3 = col[e + 3];
        for (;;) {
            int en = e + 4;
            bool more = (en + 3 < e1);
            int n0 = col[en], n1 = col[en + 1], n2 = col[en + 2], n3 = col[en + 3];
            uint2 v0 = h2[(size_t)i0 * 64 + lane];
            uint2 v1 = h2[(size_t)i1 * 64 + lane];
            uint2 v2 = h2[(size_t)i2 * 64 + lane];
            uint2 v3 = h2[(size_t)i3 * 64 + lane];
            a0 += bf16_to_f(v0.x & 0xffff); a1 += bf16_to_f(v0.x >> 16);
            a2 += bf16_to_f(v0.y & 0xffff); a3 += bf16_to_f(v0.y >> 16);
            a0 += bf16_to_f(v1.x & 0xffff); a1 += bf16_to_f(v1.x >> 16);
            a2 += bf16_to_f(v1.y & 0xffff); a3 += bf16_to_f(v1.y >> 16);
            a0 += bf16_to_f(v2.x & 0xffff); a1 += bf16_to_f(v2.x >> 16);
            a2 += bf16_to_f(v2.y & 0xffff); a3 += bf16_to_f(v2.y >> 16);
            a0 += bf16_to_f(v3.x & 0xffff); a1 += bf16_to_f(v3.x >> 16);
            a2 += bf16_to_f(v3.y & 0xffff); a3 += bf16_to_f(v3.y >> 16);
            e = en;
            if (!more) break;
            i0 = n0; i1 = n1; i2 = n2; i3 = n3;
        }
    }
    for (; e < e1; e++) {
        uint2 v = h2[(size_t)col[e] * 64 + lane];
        a0 += bf16_to_f(v.x & 0xffff); a1 += bf16_to_f(v.x >> 16);
        a2 += bf16_to_f(v.y & 0xffff); a3 += bf16_to_f(v.y >> 16);
    }
    float nm = normv[wid];
    float ox = a0 * nm, oy = a1 * nm, oz = a2 * nm, ow = a3 * nm;
    unsigned hx = bf16_rne(ox), hy = bf16_rne(oy), hz = bf16_rne(oz), hw = bf16_rne(ow);
    unsigned lx = bf16_rne(ox - bf16_to_f(hx));
    unsigned ly = bf16_rne(oy - bf16_to_f(hy));
    unsigned lz = bf16_rne(oz - bf16_to_f(hz));
    unsigned lw = bf16_rne(ow - bf16_to_f(hw));
    size_t base = (size_t)wid * 256 + lane * 4;
    *(uint2*)&Ah[base] = make_uint2(hx | (hy << 16), hz | (hw << 16));
    *(uint2*)&Al[base] = make_uint2(lx | (ly << 16), lz | (lw << 16));
}

// ---------------- split-bf16 MFMA GEMM + tanh epilogue -> bf16 output ----------------

template <int KDIM>
__global__ __launch_bounds__(256) void gemm_mfma_tanh(const ushort* __restrict__ Ah,
                                                      const ushort* __restrict__ Al,
                                                      const ushort* __restrict__ WhT,
                                                      const ushort* __restrict__ WlT,
                                                      const float* __restrict__ bias,
                                                      const float* __restrict__ betav,
                                                      ushort* __restrict__ out) {
    __shared__ ushort Ahs[128][40], Als[128][40], Whs[128][40], Wls[128][40];
    int t    = threadIdx.x;
    int lane = t & 63, wv = t >> 6;
    int rowBase = blockIdx.x * 128;
    int colBase = blockIdx.y * 128;
    f32x4 acc[2][8] = {};

    for (int k0 = 0; k0 < KDIM; k0 += 32) {
        #pragma unroll
        for (int i = 0; i < 2; i++) {
            int idx = t + i * 256;
            int r = idx >> 2, kq = idx & 3;
            size_t g = (size_t)(rowBase + r) * KDIM + k0 + kq * 8;
            *(short8*)&Ahs[r][kq * 8] = *(const short8*)&Ah[g];
            *(short8*)&Als[r][kq * 8] = *(const short8*)&Al[g];
        }
        #pragma unroll
        for (int i = 0; i < 2; i++) {
            int idx = t + i * 256;
            int c = idx >> 2, kq = idx & 3;
            size_t g = (size_t)(colBase + c) * KDIM + k0 + kq * 8;
            *(short8*)&Whs[c][kq * 8] = *(const short8*)&WhT[g];
            *(short8*)&Wls[c][kq * 8] = *(const short8*)&WlT[g];
        }
        __syncthreads();
        int rA = wv * 32 + (lane & 15);
        int kb = (lane >> 4) * 8;
        short8 ah0 = *(const short8*)&Ahs[rA][kb];
        short8 ah1 = *(const short8*)&Ahs[rA + 16][kb];
        short8 al0 = *(const short8*)&Als[rA][kb];
        short8 al1 = *(const short8*)&Als[rA + 16][kb];
        #pragma unroll
        for (int ct = 0; ct < 8; ct++) {
            int cW = ct * 16 + (lane & 15);
            short8 wh = *(const short8*)&Whs[cW][kb];
            short8 wl = *(const short8*)&Wls[cW][kb];
            acc[0][ct] = __builtin_amdgcn_mfma_f32_16x16x32_bf16(ah0, wh, acc[0][ct], 0, 0, 0);
            acc[0][ct] = __builtin_amdgcn_mfma_f32_16x16x32_bf16(ah0, wl, acc[0][ct], 0, 0, 0);
            acc[0][ct] = __builtin_amdgcn_mfma_f32_16x16x32_bf16(al0, wh, acc[0][ct], 0, 0, 0);
            acc[1][ct] = __builtin_amdgcn_mfma_f32_16x16x32_bf16(ah1, wh, acc[1][ct], 0, 0, 0);
            acc[1][ct] = __builtin_amdgcn_mfma_f32_16x16x32_bf16(ah1, wl, acc[1][ct], 0, 0, 0);
            acc[1][ct] = __builtin_amdgcn_mfma_f32_16x16x32_bf16(al1, wh, acc[1][ct], 0, 0, 0);
        }
        __syncthreads();
    }
    int cb = colBase + (lane & 15);
    #pragma unroll
    for (int rt = 0; rt < 2; rt++) {
        int rb = rowBase + wv * 32 + rt * 16 + (lane >> 4) * 4;
        #pragma unroll
        for (int j = 0; j < 4; j++) {
            int row = rb + j;
            float bt = betav[row];
            #pragma unroll
            for (int ct = 0; ct < 8; ct++) {
                int c = cb + ct * 16;
                out[(size_t)row * 256 + c] =
                    (ushort)bf16_rne(tanh_fast(acc[rt][ct][j] + bt * bias[c]));
            }
        }
    }
}

// ---------------- layer-4 GEMV: s_lin[n] = h3[n] . W4 (bf16 h3) ----------------

__global__ __launch_bounds__(256) void gemv_kernel(const ushort* __restrict__ hb,
                                                   const float* __restrict__ w4,
                                                   float* __restrict__ s_lin) {
    int wid  = (blockIdx.x * 256 + threadIdx.x) >> 6;
    int lane = threadIdx.x & 63;
    const uint2* h2 = (const uint2*)hb;
    uint2 a = h2[(size_t)wid * 64 + lane];
    float4 b = ((const float4*)w4)[lane];
    float s = bf16_to_f(a.x & 0xffff) * b.x + bf16_to_f(a.x >> 16) * b.y +
              bf16_to_f(a.y & 0xffff) * b.z + bf16_to_f(a.y >> 16) * b.w;
    s += __shfl_xor(s, 32); s += __shfl_xor(s, 16); s += __shfl_xor(s, 8);
    s += __shfl_xor(s, 4);  s += __shfl_xor(s, 2);  s += __shfl_xor(s, 1);
    if (lane == 0) s_lin[wid] = s;
}

__global__ __launch_bounds__(256) void agg_scalar_kernel(const float* __restrict__ s_lin,
                                                         const int* __restrict__ row_ptr,
                                                         const int* __restrict__ col,
                                                         const float* __restrict__ normv,
                                                         const float* __restrict__ betav,
                                                         const float* __restrict__ b4,
                                                         float* __restrict__ scores) {
    int wid  = (blockIdx.x * 256 + threadIdx.x) >> 6;
    int lane = threadIdx.x & 63;
    int e0 = row_ptr[wid], e1 = row_ptr[wid + 1];
    float sum = (lane == 0) ? s_lin[wid] : 0.0f;
    for (int e = e0 + lane; e < e1; e += 64) sum += s_lin[col[e]];
    sum += __shfl_xor(sum, 32); sum += __shfl_xor(sum, 16); sum += __shfl_xor(sum, 8);
    sum += __shfl_xor(sum, 4);  sum += __shfl_xor(sum, 2);  sum += __shfl_xor(sum, 1);
    if (lane == 0) scores[wid] = tanh_fast(normv[wid] * sum + betav[wid] * b4[0]);
}

// ---------------- per-graph descending bitonic sort, keep top-64 values ----------------

__global__ __launch_bounds__(128) void sort_kernel(const float* __restrict__ scores,
                                                   float* __restrict__ topk) {
    __shared__ float v[128];
    int b = blockIdx.x, t = threadIdx.x;
    v[t] = scores[b * NPG + t];
    __syncthreads();
    for (int k = 2; k <= 128; k <<= 1) {
        for (int j = k >> 1; j > 0; j >>= 1) {
            int ixj = t ^ j;
            if (ixj > t) {
                bool up = ((t & k) == 0);
                float a = v[t], c = v[ixj];
                bool sw = up ? (a < c) : (a > c);
                if (sw) { v[t] = c; v[ixj] = a; }
            }
            __syncthreads();
        }
    }
    if (t < KTOP) topk[b * KTOP + t] = v[t];
}

// ---------------- head ----------------

__global__ __launch_bounds__(128) void head_kernel(const float* __restrict__ topk,
                                                   const float* __restrict__ c1w,
                                                   const float* __restrict__ c1b,
                                                   const float* __restrict__ c2w,
                                                   const float* __restrict__ c2b,
                                                   const float* __restrict__ f1w,
                                                   const float* __restrict__ f1b,
                                                   const float* __restrict__ f2w,
                                                   const float* __restrict__ f2b,
                                                   float* __restrict__ out) {
    __shared__ float top[64];
    __shared__ float pool[16][32];
    __shared__ float dense[896];
    __shared__ float fc1o[128];
    int b = blockIdx.x, t = threadIdx.x;
    if (t < 64) top[t] = topk[b * KTOP + t];
    __syncthreads();
    if (t < 16) {
        float a = c1b[t];
        for (int i = 0; i < 64; i++) a += c1w[t * 769 + i] * top[i];
        float v0 = fmaxf(a, 0.0f);
        float r  = fmaxf(c1b[t], 0.0f);
        pool[t][0] = fmaxf(v0, r);
        for (int p = 1; p < 32; p++) pool[t][p] = r;
    }
    __syncthreads();
    for (int idx = t; idx < 896; idx += 128) {
        int o = idx / 28, p = idx % 28;
        float a = c2b[o];
        for (int i = 0; i < 16; i++) {
            #pragma unroll
            for (int tt = 0; tt < 5; tt++)
                a += c2w[o * 80 + i * 5 + tt] * pool[i][p + tt];
        }
        dense[idx] = fmaxf(a, 0.0f);
    }
    __syncthreads();
    {
        float a = f1b[t];
        for (int i = 0; i < 896; i++) a += f1w[i * 128 + t] * dense[i];
        fc1o[t] = fmaxf(a, 0.0f);
    }
    __syncthreads();
    if (t < 10) {
        float a = f2b[t];
        for (int i = 0; i < 128; i++) a += f2w[i * 10 + t] * fc1o[i];
        out[b * 10 + t] = a;
    }
}

// ---------------- launch ----------------

extern "C" void kernel_launch(void* const* d_in, const int* in_sizes, int n_in,
                              void* d_out, int out_size, void* d_ws, size_t ws_size,
                              hipStream_t stream) {
    const float* x   = (const float*)d_in[0];
    const int*   ei  = (const int*)d_in[1];   // int32 per harness contract
    const float* W1 = (const float*)d_in[3];
    const float* b1 = (const float*)d_in[4];
    const float* W2 = (const float*)d_in[5];
    const float* b2 = (const float*)d_in[6];
    const float* W3 = (const float*)d_in[7];
    const float* b3 = (const float*)d_in[8];
    const float* W4 = (const float*)d_in[9];
    const float* b4 = (const float*)d_in[10];
    const float* c1w = (const float*)d_in[11];
    const float* c1b = (const float*)d_in[12];
    const float* c2w = (const float*)d_in[13];
    const float* c2b = (const float*)d_in[14];
    const float* f1w = (const float*)d_in[15];
    const float* f1b = (const float*)d_in[16];
    const float* f2w = (const float*)d_in[17];
    const float* f2b = (const float*)d_in[18];
    float* out = (float*)d_out;

    // workspace layout (~122 MB)
    char* ws = (char*)d_ws;
    ushort* hbB  = (ushort*)ws;                            // 32 MB bf16 activations [N][256]
    ushort* AhG  = (ushort*)(ws + ((size_t)32 << 20));     // 32 MB bf16-hi
    ushort* AlG  = (ushort*)(ws + ((size_t)64 << 20));     // 32 MB bf16-lo
    ushort* xb   = (ushort*)(ws + ((size_t)96 << 20));     // 16 MB bf16 x [N][128]
    char* p = ws + ((size_t)112 << 20);
    auto take = [&](size_t bytes) { char* q = p; p += (bytes + 255) & ~(size_t)255; return q; };
    int*    outdeg  = (int*)take(N_NODES * 4);
    int*    indeg   = (int*)take(N_NODES * 4);
    int*    row_ptr = (int*)take((N_NODES + 1) * 4);
    int*    cursor  = (int*)take(N_NODES * 4);
    int*    col     = (int*)take(((size_t)N_EDGES + 64) * 4);  // +64 pad for prefetch
    float*  normv   = (float*)take(N_NODES * 4);
    float*  betav   = (float*)take(N_NODES * 4);
    float*  s_lin   = (float*)take(N_NODES * 4);
    float*  scores  = (float*)take(N_NODES * 4);
    float*  topk    = (float*)take(NGRAPH * KTOP * 4);
    ushort* W1hT = (ushort*)take(128 * 256 * 2);
    ushort* W1lT = (ushort*)take(128 * 256 * 2);
    ushort* W2hT = (ushort*)take(256 * 256 * 2);
    ushort* W2lT = (ushort*)take(256 * 256 * 2);
    ushort* W3hT = (ushort*)take(256 * 256 * 2);
    ushort* W3lT = (ushort*)take(256 * 256 * 2);

    // graph structure + conversions
    init_deg_kernel<<<N_NODES / 256, 256, 0, stream>>>(outdeg, indeg);
    count_range_kernel<<<2048, 256, 0, stream>>>(ei, outdeg, indeg);
    scan_kernel<<<1, 1024, 0, stream>>>(indeg, row_ptr, cursor);
    norm_beta_kernel<<<N_NODES / 256, 256, 0, stream>>>(outdeg, indeg, normv, betav);
    fill_range_kernel<<<2048, 256, 0, stream>>>(ei, cursor, col);
    xconv_kernel<<<8192, 256, 0, stream>>>(x, xb);
    wsplit_kernel<<<128, 256, 0, stream>>>(W1, W1hT, W1lT, 128);
    wsplit_kernel<<<256, 256, 0, stream>>>(W2, W2hT, W2lT, 256);
    wsplit_kernel<<<256, 256, 0, stream>>>(W3, W3hT, W3lT, 256);

    dim3 gemmGrid(N_NODES / 128, 2);

    // layer 1: bf16 x gather (256B/edge) -> hi/lo; MFMA GEMM -> bf16 h1
    agg_x_kernel<<<N_NODES / 4, 256, 0, stream>>>(xb, row_ptr, col, normv, AhG, AlG);
    gemm_mfma_tanh<128><<<gemmGrid, 256, 0, stream>>>(AhG, AlG, W1hT, W1lT, b1, betav, hbB);
    // layer 2: bf16 gather (512B/edge) -> hi/lo; GEMM -> bf16 h2
    agg_h_kernel<<<N_NODES / 4, 256, 0, stream>>>(hbB, row_ptr, col, normv, AhG, AlG);
    gemm_mfma_tanh<256><<<gemmGrid, 256, 0, stream>>>(AhG, AlG, W2hT, W2lT, b2, betav, hbB);
    // layer 3
    agg_h_kernel<<<N_NODES / 4, 256, 0, stream>>>(hbB, row_ptr, col, normv, AhG, AlG);
    gemm_mfma_tanh<256><<<gemmGrid, 256, 0, stream>>>(AhG, AlG, W3hT, W3lT, b3, betav, hbB);
    // layer 4
    gemv_kernel<<<N_NODES / 4, 256, 0, stream>>>(hbB, W4, s_lin);
    agg_scalar_kernel<<<N_NODES / 4, 256, 0, stream>>>(s_lin, row_ptr, col, normv, betav, b4, scores);

    // sort-pool + head
    sort_kernel<<<NGRAPH, 128, 0, stream>>>(scores, topk);
    head_kernel<<<NGRAPH, 128, 0, stream>>>(topk, c1w, c1b, c2w, c2b, f1w, f1b, f2w, f2b, out);
}